// Round 7
// baseline (703.579 us; speedup 1.0000x reference)
//
#include <hip/hip_runtime.h>
#include <math.h>

// Problem constants (fixed by the reference)
#define BB    8
#define LL    2048
#define DMOD  1024
#define DI    2048
#define NST   16
#define MR    (BB*LL)   // 16384 rows
// scan chunking
#define NCH   16
#define CLEN  128       // NCH*CLEN == LL
#define XDW   36        // padded xdbl row: [dt, pad,pad,pad, B0..15, C0..15]

typedef unsigned short bf16_t;
typedef __attribute__((ext_vector_type(8))) __bf16 bf16x8;
typedef __attribute__((ext_vector_type(4))) float  f32x4;

__device__ __forceinline__ float b2f(bf16_t u) {
  return __uint_as_float(((unsigned int)u) << 16);
}
// HW bf16 convert (RNE) -- 1 VALU op
__device__ __forceinline__ bf16_t f2bn(float f) {
  __bf16 h = (__bf16)f;
  return *(bf16_t*)&h;
}

__device__ __forceinline__ void cstore(float* p, float v)  { *p = v; }
__device__ __forceinline__ void cstore(bf16_t* p, float v) { *p = f2bn(v); }

// async global->LDS, 16B per lane; LDS dest = wave-uniform base + lane*16
__device__ __forceinline__ void gld16(const bf16_t* g, bf16_t* l) {
  __builtin_amdgcn_global_load_lds(
      (const __attribute__((address_space(1))) unsigned int*)g,
      (__attribute__((address_space(3))) unsigned int*)l, 16, 0, 0);
}

// softplus via 2 HW transcendentals (abs err ~1e-7, fine vs 5.5e-4 budget)
__device__ __forceinline__ float softplus(float x) {
  return (x > 20.f) ? x : __logf(1.f + __expf(x));
}
__device__ __forceinline__ float silu(float z) {
  return z * __builtin_amdgcn_rcpf(1.f + __expf(-z));
}

// ---------------------------------------------------------------------------
// fp32 -> bf16 convert (vectorized x4)
// ---------------------------------------------------------------------------
__global__ __launch_bounds__(256) void cvt_bf16(
    const float* __restrict__ in, bf16_t* __restrict__ out, int n4)
{
  int i = blockIdx.x * 256 + threadIdx.x;
  if (i >= n4) return;
  float4 v = ((const float4*)in)[i];
  ushort4 u;
  u.x = f2bn(v.x); u.y = f2bn(v.y); u.z = f2bn(v.z); u.w = f2bn(v.w);
  ((ushort4*)out)[i] = u;
}

// W_x [33,2048] fp32 -> padded bf16 [64,2048] (rows 33..63 zero)
__global__ __launch_bounds__(256) void cvt_wx(
    const float* __restrict__ W_x, bf16_t* __restrict__ Wx_bf)
{
  int i = blockIdx.x * 256 + threadIdx.x;   // 64*2048 = 131072
  int j = i >> 11;
  Wx_bf[i] = (j < 33) ? f2bn(W_x[i]) : (bf16_t)0;
}

// ---------------------------------------------------------------------------
// Phase-pipelined MFMA GEMM NT (T3+T4+T5) at 96 KB LDS.
// 256x256 tile, k-units of 32, 512 thr (8 waves: 2M x 4N, 128x64 out/wave).
// LDS: 3-buffer rotation, A[3]+B[3] regions of [256][32] bf16 = 96 KB.
// R7 fix: COUNTED lgkmcnt(N) per phase (N = ds_reads just issued for the
// NEXT phase's MFMA).  MFMA consumes frags read one phase earlier, so the
// fresh reads proceed on the LDS pipe UNDER the MFMA cluster -- this is the
// lgkm analog of T4.  (The old lgkmcnt(0) drained the fresh reads too,
// serializing LDS (1130 cyc/unit/CU) with MFMA (1243 cyc) -> 36% MfmaUtil.)
// DS ops retire in issue order -> count exact.  sched_barrier(0) after each
// wait (rule 18).  Overwrite ledger re-verified with 1-phase-later read-
// completion guarantees; every STAGE still >=1 barrier after last read done.
// ONE counted vmcnt(4) per unit (oldest-retire => unit u+1 landed).
// Chunk-XOR swizzle both-sides (bank conflicts 0, R4/R6).
// Per-acc-element K order unchanged -> bitwise-identical output.
// ---------------------------------------------------------------------------
template <typename TC>
__global__ __launch_bounds__(512) void mgemm_p3(
    const bf16_t* __restrict__ A, const bf16_t* __restrict__ B,
    TC* __restrict__ C, int N, int K)
{
  __shared__ __align__(16) bf16_t lds[49152];   // 96 KB
  const int tid  = threadIdx.x;
  const int wave = tid >> 6;
  const int lane = tid & 63;
  const int m0 = blockIdx.y * 256;
  const int n0 = blockIdx.x * 256;
  const int fr = lane & 15;
  const int quad = lane >> 4;
  const int wm = (wave >> 2) * 128;   // 2 wave-rows
  const int wn = (wave & 3) * 64;     // 4 wave-cols

  // staging: one gld16 line = 512 thr x 16B = 8KB = 128 rows x 32 elems
  const int srow = tid >> 2;
  const int ssw  = (tid & 3) ^ ((srow >> 1) & 3);   // pre-swizzled chunk
  const bf16_t* Asrc = A + (size_t)(m0 + srow) * K + ssw * 8;
  const bf16_t* Bsrc = B + (size_t)(n0 + srow) * K + ssw * 8;
  const size_t r128 = (size_t)128 * K;

  // swizzled ds_read offsets (elements, region-relative [256][32])
  int aoff[8], boff[4];
#pragma unroll
  for (int i = 0; i < 8; ++i) {
    int row = wm + i * 16 + fr;
    aoff[i] = row * 32 + ((quad ^ ((row >> 1) & 3)) * 8);
  }
#pragma unroll
  for (int j = 0; j < 4; ++j) {
    int row = wn + j * 16 + fr;
    boff[j] = row * 32 + ((quad ^ ((row >> 1) & 3)) * 8);
  }

#define AB_(u) (((u) % 3) * 8192)
#define BB_(u) (24576 + ((u) % 3) * 8192)
#define STAGE_A(u) do {                                                    \
    const bf16_t* s_ = Asrc + (size_t)(u) * 32;                            \
    bf16_t* l_ = lds + AB_(u) + wave * 512;                                \
    gld16(s_, l_); gld16(s_ + r128, l_ + 4096);                            \
  } while (0)
#define STAGE_B(u) do {                                                    \
    const bf16_t* s_ = Bsrc + (size_t)(u) * 32;                            \
    bf16_t* l_ = lds + BB_(u) + wave * 512;                                \
    gld16(s_, l_); gld16(s_ + r128, l_ + 4096);                            \
  } while (0)
#define LDA4(dst,u,ib) do {                                                \
    const bf16_t* r_ = lds + AB_(u);                                       \
    _Pragma("unroll")                                                      \
    for (int i_ = 0; i_ < 4; ++i_)                                         \
      dst[i_] = *(const bf16x8*)&r_[aoff[(ib) + i_]];                      \
  } while (0)
#define LDB4(dst,u) do {                                                   \
    const bf16_t* r_ = lds + BB_(u);                                       \
    _Pragma("unroll")                                                      \
    for (int j_ = 0; j_ < 4; ++j_)                                         \
      dst[j_] = *(const bf16x8*)&r_[boff[j_]];                             \
  } while (0)
#define MM16(ar,br,ib) do {                                                \
    __builtin_amdgcn_s_setprio(1);                                         \
    _Pragma("unroll")                                                      \
    for (int i_ = 0; i_ < 4; ++i_)                                         \
      _Pragma("unroll")                                                    \
      for (int j_ = 0; j_ < 4; ++j_)                                       \
        acc[(ib) + i_][j_] = __builtin_amdgcn_mfma_f32_16x16x32_bf16(      \
            ar[i_], br[j_], acc[(ib) + i_][j_], 0, 0, 0);                  \
    __builtin_amdgcn_s_setprio(0);                                         \
  } while (0)
#define BAR()   __builtin_amdgcn_s_barrier()
// counted lgkm wait: all but the n newest DS reads are complete
#define LGKMC(n) do { asm volatile("s_waitcnt lgkmcnt(" #n ")" ::: "memory"); \
                      __builtin_amdgcn_sched_barrier(0); } while (0)
#define VMBAR(n) asm volatile("s_waitcnt vmcnt(" #n ")\n\ts_barrier" ::: "memory")

  f32x4 acc[8][4];
#pragma unroll
  for (int i = 0; i < 8; ++i)
#pragma unroll
    for (int j = 0; j < 4; ++j) acc[i][j] = (f32x4){0.f, 0.f, 0.f, 0.f};

  // even-unit sets (aC0=a03, aQ0=a47, bC0), odd-unit sets (aC1,aQ1,bC1)
  bf16x8 aC0[4], aQ0[4], bC0[4], aC1[4], aQ1[4], bC1[4];

  const int nu = K >> 5;   // k-units of 32; nu even, >= 4

  // prologue: stage units 0,1; land unit 0; unit0-P1 (reads, no MFMA)
  STAGE_B(0); STAGE_A(0); STAGE_B(1); STAGE_A(1);   // 8 loads
  VMBAR(4);                                          // unit0 landed
  LDA4(aC0, 0, 0); LDB4(bC0, 0);
  STAGE_B(2);
  BAR(); LGKMC(0); BAR();

  for (int u = 0; u < nu; u += 2) {
    const bool s2 = (u + 2 < nu), s3 = (u + 3 < nu), s4 = (u + 4 < nu);
    // ---- even P2: read a47[u] (4 new); stage A(u+2); MFMA(a03[u],b[u])
    LDA4(aQ0, u, 4);
    if (s2) STAGE_A(u + 2);
    BAR(); LGKMC(4);                                 // aC0,bC0 done; aQ0 flies
    MM16(aC0, bC0, 0);
    if (s2) VMBAR(4); else VMBAR(0);                 // unit u+1 landed
    // ---- odd P1: read a03[u+1],b[u+1] (8 new); stage B(u+3); MFMA(a47[u],b[u])
    LDA4(aC1, u + 1, 0); LDB4(bC1, u + 1);
    if (s3) STAGE_B(u + 3);
    BAR(); LGKMC(8);                                 // aQ0 done; aC1,bC1 fly
    MM16(aQ0, bC0, 4);
    BAR();
    // ---- odd P2: read a47[u+1] (4 new); stage A(u+3); MFMA(a03[u+1],b[u+1])
    LDA4(aQ1, u + 1, 4);
    if (s3) STAGE_A(u + 3);
    BAR(); LGKMC(4);                                 // aC1,bC1 done; aQ1 flies
    MM16(aC1, bC1, 0);
    if (s3) VMBAR(4); else VMBAR(0);                 // unit u+2 landed
    // ---- next even P1: read a03[u+2],b[u+2] (8 new); stage B(u+4); MFMA(a47[u+1],b[u+1])
    if (s2) { LDA4(aC0, u + 2, 0); LDB4(bC0, u + 2); }
    if (s4) STAGE_B(u + 4);
    BAR();
    if (s2) { LGKMC(8); } else { LGKMC(0); }         // aQ1 done
    MM16(aQ1, bC1, 4);
    BAR();
  }

  // D col = lane&15, row = quad*4 + r (verified mapping)
#pragma unroll
  for (int i = 0; i < 8; ++i)
#pragma unroll
    for (int j = 0; j < 4; ++j) {
#pragma unroll
      for (int r = 0; r < 4; ++r) {
        int grow = m0 + wm + i * 16 + quad * 4 + r;
        int gcol = n0 + wn + j * 16 + fr;
        cstore(&C[(size_t)grow * N + gcol], acc[i][j][r]);
      }
    }
#undef AB_
#undef BB_
#undef STAGE_A
#undef STAGE_B
#undef LDA4
#undef LDB4
#undef MM16
#undef BAR
#undef LGKMC
#undef VMBAR
}

// ---------------------------------------------------------------------------
// x_dbl MFMA GEMM: xdbl[M,36pad] = xs[M,2048] * Wx_bf[64,2048]^T.
// BM=64, BK=64, 4 waves; wave w owns row-tile w, 3 col-tiles. grid = MR/64.
// Output row layout: dt at col 0, B at 4..19, C at 20..35.
// ---------------------------------------------------------------------------
__global__ __launch_bounds__(256) void xdbl_mfma(
    const bf16_t* __restrict__ xs, const bf16_t* __restrict__ Wx_bf,
    float* __restrict__ xdbl)
{
  __shared__ __align__(16) bf16_t As[2 * 64 * 32];
  __shared__ __align__(16) bf16_t Bs[2 * 64 * 32];
  const int tid  = threadIdx.x;
  const int wave = tid >> 6;
  const int lane = tid & 63;
  const int m0 = blockIdx.x * 64;
  const int fr = lane & 15;
  const int quad = lane >> 4;

  const int srow = wave * 16 + (lane >> 2);
  const int scol = (lane & 3) * 8;
  const bf16_t* Ag = xs + (size_t)(m0 + srow) * DI + scol;
  const bf16_t* Bg = Wx_bf + (size_t)srow * DI + scol;
  bf16_t* lA = As + wave * 512;
  bf16_t* lB = Bs + wave * 512;

  f32x4 acc[3];
#pragma unroll
  for (int jt = 0; jt < 3; ++jt) acc[jt] = (f32x4){0.f, 0.f, 0.f, 0.f};

  for (int k0 = 0; k0 < DI; k0 += 64) {
    __syncthreads();
#pragma unroll
    for (int kk = 0; kk < 2; ++kk) {
      gld16(Ag + k0 + kk * 32, lA + kk * 2048);
      gld16(Bg + k0 + kk * 32, lB + kk * 2048);
    }
    __syncthreads();

#pragma unroll
    for (int kk = 0; kk < 2; ++kk) {
      bf16x8 a = *(const bf16x8*)&As[kk * 2048 + (wave * 16 + fr) * 32 + quad * 8];
#pragma unroll
      for (int jt = 0; jt < 3; ++jt) {
        bf16x8 b = *(const bf16x8*)&Bs[kk * 2048 + (jt * 16 + fr) * 32 + quad * 8];
        acc[jt] = __builtin_amdgcn_mfma_f32_16x16x32_bf16(a, b, acc[jt], 0, 0, 0);
      }
    }
  }

#pragma unroll
  for (int jt = 0; jt < 3; ++jt) {
#pragma unroll
    for (int r = 0; r < 4; ++r) {
      int grow = m0 + wave * 16 + quad * 4 + r;
      int j = jt * 16 + fr;
      if (j < 33) {
        int col = (j == 0) ? 0 : (j + 3);
        xdbl[(size_t)grow * XDW + col] = acc[jt][r];
      }
    }
  }
}

// ---------------------------------------------------------------------------
// Causal depthwise conv1d (k=4) + bias + SiLU.  bf16 xz -> bf16 xs.
// ---------------------------------------------------------------------------
__global__ __launch_bounds__(256) void conv_silu(
    const bf16_t* __restrict__ xz, const float* __restrict__ cw,
    const float* __restrict__ cb, bf16_t* __restrict__ xs)
{
  int idx = blockIdx.x * 256 + threadIdx.x;
  int d4 = idx & 511;
  int l  = (idx >> 9) & 2047;
  int b  = idx >> 20;
  int d  = d4 * 4;

  float wch[4][4];
#pragma unroll
  for (int c = 0; c < 4; ++c)
#pragma unroll
    for (int k = 0; k < 4; ++k) wch[c][k] = cw[(d + c) * 4 + k];

  float acc0 = cb[d+0], acc1 = cb[d+1], acc2 = cb[d+2], acc3 = cb[d+3];
  size_t rowbase = ((size_t)b * LL + l) * 4096 + d;
#pragma unroll
  for (int k = 0; k < 4; ++k) {
    if (l - 3 + k >= 0) {
      ushort4 u = *(const ushort4*)(xz + rowbase - (size_t)(3 - k) * 4096);
      acc0 += b2f(u.x) * wch[0][k];
      acc1 += b2f(u.y) * wch[1][k];
      acc2 += b2f(u.z) * wch[2][k];
      acc3 += b2f(u.w) * wch[3][k];
    }
  }
  ushort4 o;
  o.x = f2bn(silu(acc0)); o.y = f2bn(silu(acc1));
  o.z = f2bn(silu(acc2)); o.w = f2bn(silu(acc3));
  *(ushort4*)(xs + ((size_t)b * LL + l) * (size_t)DI + d) = o;
}

// ---------------------------------------------------------------------------
// Scan pass 1: per (b, chunk) scan from h=0; ONE channel per thread.
// grid: 1024 = b(8) x chunk(16) x dgroup(8); thread covers d = dg*256+tid.
// FAST PATH: A[d,n] = -(n+1) => exp2(dt*A2[n]) = w^(n+1), w = exp2(dt*A2_0).
// Verified per thread vs A_log; block-uniform fallback otherwise.
// states: [b][c][d][32] fp32 (0..15 P, 16..31 h_end).
// ---------------------------------------------------------------------------
__global__ __launch_bounds__(256) void scan_pass1(
    const float* __restrict__ xdbl, const bf16_t* __restrict__ xs,
    const float* __restrict__ W_dt, const float* __restrict__ b_dt,
    const float* __restrict__ A_log, float* __restrict__ states)
{
  const int bid = blockIdx.x;
  const int dg = bid & 7, c = (bid >> 3) & 15, b = bid >> 7;
  const int d = dg * 256 + threadIdx.x;

  const float A2_0 = -__expf(A_log[(size_t)d * NST]) * 1.44269504f;
  bool ok = true;
#pragma unroll
  for (int n = 1; n < NST; ++n) {
    float a = -__expf(A_log[(size_t)d * NST + n]) * 1.44269504f;
    ok = ok && (fabsf(a - (float)(n + 1) * A2_0) <= 1e-3f * (float)(n + 1));
  }
  __shared__ int s_ok;
  __shared__ float sx[64 * XDW];
  if (threadIdx.x == 0) s_ok = 1;
  __syncthreads();
  if (!ok) s_ok = 0;           // benign race: only 0 is written
  __syncthreads();
  const bool fast = (s_ok != 0);

  float h[NST];
#pragma unroll
  for (int n = 0; n < NST; ++n) h[n] = 0.f;
  const float wdt = W_dt[d], bdt = b_dt[d];
  float dts = 0.f;
  const size_t rbase = (size_t)b * LL + c * CLEN;
  float xv = b2f(xs[rbase * DI + d]);

  if (fast) {
    for (int s = 0; s < CLEN; s += 64) {
      __syncthreads();
      const float* xg = xdbl + (rbase + s) * XDW;
      for (int q = threadIdx.x; q < 64 * XDW; q += 256) sx[q] = xg[q];
      __syncthreads();
#pragma unroll 2
      for (int u = 0; u < 64; ++u) {
        int tn = s + u + 1;
        float nx = 0.f;
        if (tn < CLEN) nx = b2f(xs[(rbase + tn) * DI + d]);
        float dtr = sx[u * XDW];
        float dt = softplus(fmaf(dtr, wdt, bdt));
        dts += dt;
        float dx = dt * xv;
        float wv[NST];
        wv[0] = exp2f(dt * A2_0);
#pragma unroll
        for (int n = 1; n < NST; ++n)
          wv[n] = wv[(n - 1) >> 1] * wv[n - 1 - ((n - 1) >> 1)];  // w^(n+1), depth 4
        const float4* Bp = (const float4*)&sx[u * XDW + 4];
#pragma unroll
        for (int n4 = 0; n4 < 4; ++n4) {
          float4 Bv = Bp[n4];
          float bb[4] = {Bv.x, Bv.y, Bv.z, Bv.w};
#pragma unroll
          for (int k = 0; k < 4; ++k) {
            int n = n4 * 4 + k;
            h[n] = fmaf(wv[n], h[n], dx * bb[k]);
          }
        }
        xv = nx;
      }
    }
    size_t sb = (((size_t)b * NCH + c) * DI + d) * 32;
    float Wv[NST];
    Wv[0] = exp2f(dts * A2_0);
#pragma unroll
    for (int n = 1; n < NST; ++n)
      Wv[n] = Wv[(n - 1) >> 1] * Wv[n - 1 - ((n - 1) >> 1)];
#pragma unroll
    for (int n = 0; n < NST; ++n) {
      states[sb + n]      = Wv[n];
      states[sb + 16 + n] = h[n];
    }
  } else {
    float A2[NST];
#pragma unroll
    for (int n = 0; n < NST; ++n)
      A2[n] = -__expf(A_log[(size_t)d * NST + n]) * 1.44269504f;
    for (int s = 0; s < CLEN; s += 64) {
      __syncthreads();
      const float* xg = xdbl + (rbase + s) * XDW;
      for (int q = threadIdx.x; q < 64 * XDW; q += 256) sx[q] = xg[q];
      __syncthreads();
#pragma unroll 2
      for (int u = 0; u < 64; ++u) {
        int tn = s + u + 1;
        float nx = 0.f;
        if (tn < CLEN) nx = b2f(xs[(rbase + tn) * DI + d]);
        float dtr = sx[u * XDW];
        float dt = softplus(fmaf(dtr, wdt, bdt));
        dts += dt;
        float dx = dt * xv;
        const float4* Bp = (const float4*)&sx[u * XDW + 4];
#pragma unroll
        for (int n4 = 0; n4 < 4; ++n4) {
          float4 Bv = Bp[n4];
          float bb[4] = {Bv.x, Bv.y, Bv.z, Bv.w};
#pragma unroll
          for (int k = 0; k < 4; ++k) {
            int n = n4 * 4 + k;
            h[n] = fmaf(exp2f(dt * A2[n]), h[n], dx * bb[k]);
          }
        }
        xv = nx;
      }
    }
    size_t sb = (((size_t)b * NCH + c) * DI + d) * 32;
#pragma unroll
    for (int n = 0; n < NST; ++n) {
      states[sb + n]      = exp2f(dts * A2[n]);
      states[sb + 16 + n] = h[n];
    }
  }
}

// ---------------------------------------------------------------------------
// Scan pass 2: compose chunk states sequentially; h_init -> P slot (in place).
// ---------------------------------------------------------------------------
__global__ __launch_bounds__(256) void scan_pass2(float* __restrict__ states)
{
  int t = blockIdx.x * 256 + threadIdx.x;    // 8*2048*16 = 262144
  int n = t & 15, d = (t >> 4) & 2047, b = t >> 15;
  float h = 0.f;
  for (int c = 0; c < NCH; ++c) {
    size_t sb = (((size_t)b * NCH + c) * DI + d) * 32;
    float P  = states[sb + n];
    float h0 = states[sb + 16 + n];
    states[sb + n] = h;          // h_init entering chunk c
    h = fmaf(P, h, h0);
  }
}

// ---------------------------------------------------------------------------
// Scan pass 3: re-scan from h_init; y = C.h + D*x; gate SiLU(z); bf16 in place.
// ONE channel per thread; same FAST-path power-chain trick as pass 1.
// ---------------------------------------------------------------------------
__global__ __launch_bounds__(256) void scan_pass3(
    const float* __restrict__ xdbl, const bf16_t* __restrict__ xz,
    bf16_t* __restrict__ xs, const float* __restrict__ states,
    const float* __restrict__ W_dt, const float* __restrict__ b_dt,
    const float* __restrict__ A_log, const float* __restrict__ Dp)
{
  const int bid = blockIdx.x;
  const int dg = bid & 7, c = (bid >> 3) & 15, b = bid >> 7;
  const int d = dg * 256 + threadIdx.x;

  const float A2_0 = -__expf(A_log[(size_t)d * NST]) * 1.44269504f;
  bool ok = true;
#pragma unroll
  for (int n = 1; n < NST; ++n) {
    float a = -__expf(A_log[(size_t)d * NST + n]) * 1.44269504f;
    ok = ok && (fabsf(a - (float)(n + 1) * A2_0) <= 1e-3f * (float)(n + 1));
  }
  __shared__ int s_ok;
  __shared__ float sx[64 * XDW];
  if (threadIdx.x == 0) s_ok = 1;
  __syncthreads();
  if (!ok) s_ok = 0;
  __syncthreads();
  const bool fast = (s_ok != 0);

  float h[NST];
  size_t sb = (((size_t)b * NCH + c) * DI + d) * 32;
#pragma unroll
  for (int n = 0; n < NST; ++n) h[n] = states[sb + n];
  const float wdt = W_dt[d], bdt = b_dt[d];
  const float Dd = Dp[d];
  const size_t rbase = (size_t)b * LL + c * CLEN;

  float xv = b2f(xs[rbase * DI + d]);
  float zv = b2f(xz[rbase * 4096 + DI + d]);

  if (fast) {
    for (int s = 0; s < CLEN; s += 64) {
      __syncthreads();
      const float* xg = xdbl + (rbase + s) * XDW;
      for (int q = threadIdx.x; q < 64 * XDW; q += 256) sx[q] = xg[q];
      __syncthreads();
#pragma unroll 2
      for (int u = 0; u < 64; ++u) {
        size_t r = rbase + s + u;
        int tn = s + u + 1;
        float nx = 0.f, nz = 0.f;
        if (tn < CLEN) {
          nx = b2f(xs[(rbase + tn) * DI + d]);
          nz = b2f(xz[(rbase + tn) * 4096 + DI + d]);
        }
        float dtr = sx[u * XDW];
        float dt = softplus(fmaf(dtr, wdt, bdt));
        float dx = dt * xv;
        float y = Dd * xv;
        float wv[NST];
        wv[0] = exp2f(dt * A2_0);
#pragma unroll
        for (int n = 1; n < NST; ++n)
          wv[n] = wv[(n - 1) >> 1] * wv[n - 1 - ((n - 1) >> 1)];
        const float4* Bp = (const float4*)&sx[u * XDW + 4];
        const float4* Cp = (const float4*)&sx[u * XDW + 20];
#pragma unroll
        for (int n4 = 0; n4 < 4; ++n4) {
          float4 Bv = Bp[n4];
          float4 Cv = Cp[n4];
          float bb[4] = {Bv.x, Bv.y, Bv.z, Bv.w};
          float cc[4] = {Cv.x, Cv.y, Cv.z, Cv.w};
#pragma unroll
          for (int k = 0; k < 4; ++k) {
            int n = n4 * 4 + k;
            h[n] = fmaf(wv[n], h[n], dx * bb[k]);
            y = fmaf(h[n], cc[k], y);
          }
        }
        xs[r * DI + d] = f2bn(y * silu(zv));
        xv = nx; zv = nz;
      }
    }
  } else {
    float A2[NST];
#pragma unroll
    for (int n = 0; n < NST; ++n)
      A2[n] = -__expf(A_log[(size_t)d * NST + n]) * 1.44269504f;
    for (int s = 0; s < CLEN; s += 64) {
      __syncthreads();
      const float* xg = xdbl + (rbase + s) * XDW;
      for (int q = threadIdx.x; q < 64 * XDW; q += 256) sx[q] = xg[q];
      __syncthreads();
#pragma unroll 2
      for (int u = 0; u < 64; ++u) {
        size_t r = rbase + s + u;
        int tn = s + u + 1;
        float nx = 0.f, nz = 0.f;
        if (tn < CLEN) {
          nx = b2f(xs[(rbase + tn) * DI + d]);
          nz = b2f(xz[(rbase + tn) * 4096 + DI + d]);
        }
        float dtr = sx[u * XDW];
        float dt = softplus(fmaf(dtr, wdt, bdt));
        float dx = dt * xv;
        float y = Dd * xv;
        const float4* Bp = (const float4*)&sx[u * XDW + 4];
        const float4* Cp = (const float4*)&sx[u * XDW + 20];
#pragma unroll
        for (int n4 = 0; n4 < 4; ++n4) {
          float4 Bv = Bp[n4];
          float4 Cv = Cp[n4];
          float bb[4] = {Bv.x, Bv.y, Bv.z, Bv.w};
          float cc[4] = {Cv.x, Cv.y, Cv.z, Cv.w};
#pragma unroll
          for (int k = 0; k < 4; ++k) {
            int n = n4 * 4 + k;
            h[n] = fmaf(exp2f(dt * A2[n]), h[n], dx * bb[k]);
            y = fmaf(h[n], cc[k], y);
          }
        }
        xs[r * DI + d] = f2bn(y * silu(zv));
        xv = nx; zv = nz;
      }
    }
  }
}

// ---------------------------------------------------------------------------
extern "C" void kernel_launch(void* const* d_in, const int* in_sizes, int n_in,
                              void* d_out, int out_size, void* d_ws, size_t ws_size,
                              hipStream_t stream)
{
  const float* x     = (const float*)d_in[0];
  const float* W_in  = (const float*)d_in[1];
  const float* cw    = (const float*)d_in[2];
  const float* cb    = (const float*)d_in[3];
  const float* W_x   = (const float*)d_in[4];
  const float* W_dt  = (const float*)d_in[5];
  const float* b_dt  = (const float*)d_in[6];
  const float* A_log = (const float*)d_in[7];
  const float* Dp    = (const float*)d_in[8];
  const float* W_out = (const float*)d_in[9];
  float* out = (float*)d_out;

  // ws (proven-safe footprint): xz bf16 [16384,4096] | xs bf16 [16384,2048]
  bf16_t* xz = (bf16_t*)d_ws;
  bf16_t* xs = xz + (size_t)MR * 4096;

  // d_out (64 MiB fp32) as phase-disjoint scratch:
  //   conversions: x_bf [0,32M) | Win_bf [32M,40M) | Wx_bf [40M,40.25M)
  //   scan:        states [0,33.6M) | xdbl [33.6M,36M)  (x_bf/Win_bf dead)
  //   GEMM3 output overwrites everything last.
  bf16_t* x_bf    = (bf16_t*)d_out;
  bf16_t* Win_bf  = x_bf + (size_t)MR * DMOD;
  bf16_t* Wx_bf   = Win_bf + (size_t)4096 * DMOD;
  float*  states  = (float*)d_out;
  float*  xdbl    = states + (size_t)BB * NCH * DI * 32;   // 8.39M floats in
  bf16_t* Wout_bf = xz;   // overlays dead xz after scan pass 3

  // 0) operand conversions
  cvt_bf16<<<(MR*DMOD/4 + 255)/256, 256, 0, stream>>>(x, x_bf, MR*DMOD/4);
  cvt_bf16<<<(4096*DMOD/4 + 255)/256, 256, 0, stream>>>(W_in, Win_bf, 4096*DMOD/4);
  cvt_wx<<<(64*DI)/256, 256, 0, stream>>>(W_x, Wx_bf);
  // 1) xz = x @ W_in^T   (M=16384, N=4096, K=1024) phase-pipelined 256^2
  mgemm_p3<bf16_t><<<dim3(4096/256, MR/256), 512, 0, stream>>>(x_bf, Win_bf, xz, 4096, DMOD);
  // 2) causal depthwise conv + bias + SiLU -> xs (bf16)
  conv_silu<<<(BB*LL*512)/256, 256, 0, stream>>>(xz, cw, cb, xs);
  // 3) x_dbl (padded rows) = xs @ W_x^T (MFMA)
  xdbl_mfma<<<MR/64, 256, 0, stream>>>(xs, Wx_bf, xdbl);
  // 4) chunked selective scan (3 passes) + D*xs + SiLU(z) gate, in place in xs
  scan_pass1<<<BB*NCH*8, 256, 0, stream>>>(xdbl, xs, W_dt, b_dt, A_log, states);
  scan_pass2<<<(BB*DI*NST)/256, 256, 0, stream>>>(states);
  scan_pass3<<<BB*NCH*8, 256, 0, stream>>>(xdbl, xz, xs, states, W_dt, b_dt, A_log, Dp);
  // 5) W_out -> bf16 (dead xz region), then out = gated @ W_out^T
  cvt_bf16<<<(DMOD*DI/4 + 255)/256, 256, 0, stream>>>(W_out, Wout_bf, DMOD*DI/4);
  // out = gated @ W_out^T  (M=16384, N=1024, K=2048)
  mgemm_p3<float><<<dim3(DMOD/256, MR/256), 512, 0, stream>>>(xs, Wout_bf, out, DMOD, DI);
}

// Round 8
// 673.402 us; speedup vs baseline: 1.0448x; 1.0448x over previous
//
#include <hip/hip_runtime.h>
#include <math.h>

// Problem constants (fixed by the reference)
#define BB    8
#define LL    2048
#define DMOD  1024
#define DI    2048
#define NST   16
#define MR    (BB*LL)   // 16384 rows
// scan chunking
#define NCH   16
#define CLEN  128       // NCH*CLEN == LL
#define XDW   36        // padded xdbl row: [dt, pad,pad,pad, B0..15, C0..15]

typedef unsigned short bf16_t;
typedef __attribute__((ext_vector_type(8))) __bf16 bf16x8;
typedef __attribute__((ext_vector_type(4))) float  f32x4;
typedef __attribute__((ext_vector_type(2))) float  f32x2;

__device__ __forceinline__ float b2f(bf16_t u) {
  return __uint_as_float(((unsigned int)u) << 16);
}
// HW bf16 convert (RNE) -- 1 VALU op
__device__ __forceinline__ bf16_t f2bn(float f) {
  __bf16 h = (__bf16)f;
  return *(bf16_t*)&h;
}

__device__ __forceinline__ void cstore(float* p, float v)  { *p = v; }
__device__ __forceinline__ void cstore(bf16_t* p, float v) { *p = f2bn(v); }

// async global->LDS, 16B per lane; LDS dest = wave-uniform base + lane*16
__device__ __forceinline__ void gld16(const bf16_t* g, bf16_t* l) {
  __builtin_amdgcn_global_load_lds(
      (const __attribute__((address_space(1))) unsigned int*)g,
      (__attribute__((address_space(3))) unsigned int*)l, 16, 0, 0);
}

// softplus via 2 HW transcendentals (abs err ~1e-7, fine vs 5.5e-4 budget)
__device__ __forceinline__ float softplus(float x) {
  return (x > 20.f) ? x : __logf(1.f + __expf(x));
}
__device__ __forceinline__ float silu(float z) {
  return z * __builtin_amdgcn_rcpf(1.f + __expf(-z));
}

// ---------------------------------------------------------------------------
// fp32 -> bf16 convert (vectorized x4)
// ---------------------------------------------------------------------------
__global__ __launch_bounds__(256) void cvt_bf16(
    const float* __restrict__ in, bf16_t* __restrict__ out, int n4)
{
  int i = blockIdx.x * 256 + threadIdx.x;
  if (i >= n4) return;
  float4 v = ((const float4*)in)[i];
  ushort4 u;
  u.x = f2bn(v.x); u.y = f2bn(v.y); u.z = f2bn(v.z); u.w = f2bn(v.w);
  ((ushort4*)out)[i] = u;
}

// W_x [33,2048] fp32 -> padded bf16 [64,2048] (rows 33..63 zero)
__global__ __launch_bounds__(256) void cvt_wx(
    const float* __restrict__ W_x, bf16_t* __restrict__ Wx_bf)
{
  int i = blockIdx.x * 256 + threadIdx.x;   // 64*2048 = 131072
  int j = i >> 11;
  Wx_bf[i] = (j < 33) ? f2bn(W_x[i]) : (bf16_t)0;
}

// ---------------------------------------------------------------------------
// Phase-pipelined MFMA GEMM NT (T3+T4+T5) at 96 KB LDS -- R6 configuration
// (lgkmcnt(0); R7's counted-lgkm variant measured -5%, reverted).
// 256x256 tile, k-units of 32, 512 thr (8 waves: 2M x 4N, 128x64 out/wave).
// LDS: 3-buffer rotation, A[3]+B[3] regions of [256][32] bf16 = 96 KB.
// ONE counted vmcnt(4) per unit (oldest-retire => unit u+1 landed; >=2-phase
// issue->wait slack).  Chunk-XOR swizzle both-sides (bank conflicts 0).
// Per-acc-element K order unchanged -> bitwise-identical output.
// ---------------------------------------------------------------------------
template <typename TC>
__global__ __launch_bounds__(512) void mgemm_p3(
    const bf16_t* __restrict__ A, const bf16_t* __restrict__ B,
    TC* __restrict__ C, int N, int K)
{
  __shared__ __align__(16) bf16_t lds[49152];   // 96 KB
  const int tid  = threadIdx.x;
  const int wave = tid >> 6;
  const int lane = tid & 63;
  const int m0 = blockIdx.y * 256;
  const int n0 = blockIdx.x * 256;
  const int fr = lane & 15;
  const int quad = lane >> 4;
  const int wm = (wave >> 2) * 128;   // 2 wave-rows
  const int wn = (wave & 3) * 64;     // 4 wave-cols

  // staging: one gld16 line = 512 thr x 16B = 8KB = 128 rows x 32 elems
  const int srow = tid >> 2;
  const int ssw  = (tid & 3) ^ ((srow >> 1) & 3);   // pre-swizzled chunk
  const bf16_t* Asrc = A + (size_t)(m0 + srow) * K + ssw * 8;
  const bf16_t* Bsrc = B + (size_t)(n0 + srow) * K + ssw * 8;
  const size_t r128 = (size_t)128 * K;

  // swizzled ds_read offsets (elements, region-relative [256][32])
  int aoff[8], boff[4];
#pragma unroll
  for (int i = 0; i < 8; ++i) {
    int row = wm + i * 16 + fr;
    aoff[i] = row * 32 + ((quad ^ ((row >> 1) & 3)) * 8);
  }
#pragma unroll
  for (int j = 0; j < 4; ++j) {
    int row = wn + j * 16 + fr;
    boff[j] = row * 32 + ((quad ^ ((row >> 1) & 3)) * 8);
  }

#define AB_(u) (((u) % 3) * 8192)
#define BB_(u) (24576 + ((u) % 3) * 8192)
#define STAGE_A(u) do {                                                    \
    const bf16_t* s_ = Asrc + (size_t)(u) * 32;                            \
    bf16_t* l_ = lds + AB_(u) + wave * 512;                                \
    gld16(s_, l_); gld16(s_ + r128, l_ + 4096);                            \
  } while (0)
#define STAGE_B(u) do {                                                    \
    const bf16_t* s_ = Bsrc + (size_t)(u) * 32;                            \
    bf16_t* l_ = lds + BB_(u) + wave * 512;                                \
    gld16(s_, l_); gld16(s_ + r128, l_ + 4096);                            \
  } while (0)
#define LDA4(dst,u,ib) do {                                                \
    const bf16_t* r_ = lds + AB_(u);                                       \
    _Pragma("unroll")                                                      \
    for (int i_ = 0; i_ < 4; ++i_)                                         \
      dst[i_] = *(const bf16x8*)&r_[aoff[(ib) + i_]];                      \
  } while (0)
#define LDB4(dst,u) do {                                                   \
    const bf16_t* r_ = lds + BB_(u);                                       \
    _Pragma("unroll")                                                      \
    for (int j_ = 0; j_ < 4; ++j_)                                         \
      dst[j_] = *(const bf16x8*)&r_[boff[j_]];                             \
  } while (0)
#define MM16(ar,br,ib) do {                                                \
    __builtin_amdgcn_s_setprio(1);                                         \
    _Pragma("unroll")                                                      \
    for (int i_ = 0; i_ < 4; ++i_)                                         \
      _Pragma("unroll")                                                    \
      for (int j_ = 0; j_ < 4; ++j_)                                       \
        acc[(ib) + i_][j_] = __builtin_amdgcn_mfma_f32_16x16x32_bf16(      \
            ar[i_], br[j_], acc[(ib) + i_][j_], 0, 0, 0);                  \
    __builtin_amdgcn_s_setprio(0);                                         \
  } while (0)
#define BAR()   __builtin_amdgcn_s_barrier()
#define LGKM0() do { asm volatile("s_waitcnt lgkmcnt(0)" ::: "memory");    \
                     __builtin_amdgcn_sched_barrier(0); } while (0)
#define VMBAR(n) asm volatile("s_waitcnt vmcnt(" #n ")\n\ts_barrier" ::: "memory")

  f32x4 acc[8][4];
#pragma unroll
  for (int i = 0; i < 8; ++i)
#pragma unroll
    for (int j = 0; j < 4; ++j) acc[i][j] = (f32x4){0.f, 0.f, 0.f, 0.f};

  // even-unit sets (aC0=a03, aQ0=a47, bC0), odd-unit sets (aC1,aQ1,bC1)
  bf16x8 aC0[4], aQ0[4], bC0[4], aC1[4], aQ1[4], bC1[4];

  const int nu = K >> 5;   // k-units of 32; nu even, >= 4

  // prologue: stage units 0,1; land unit 0; unit0-P1 (reads, no MFMA)
  STAGE_B(0); STAGE_A(0); STAGE_B(1); STAGE_A(1);   // 8 loads
  VMBAR(4);                                          // unit0 landed
  LDA4(aC0, 0, 0); LDB4(bC0, 0);
  STAGE_B(2);
  BAR(); LGKM0(); BAR();

  for (int u = 0; u < nu; u += 2) {
    const bool s2 = (u + 2 < nu), s3 = (u + 3 < nu), s4 = (u + 4 < nu);
    // ---- even P2: read a47[u]; stage A(u+2); MFMA(a03[u],b[u])
    LDA4(aQ0, u, 4);
    if (s2) STAGE_A(u + 2);
    BAR(); LGKM0();
    MM16(aC0, bC0, 0);
    if (s2) VMBAR(4); else VMBAR(0);                 // unit u+1 landed
    // ---- odd P1: read a03[u+1],b[u+1]; stage B(u+3); MFMA(a47[u],b[u])
    LDA4(aC1, u + 1, 0); LDB4(bC1, u + 1);
    if (s3) STAGE_B(u + 3);
    BAR(); LGKM0();
    MM16(aQ0, bC0, 4);
    BAR();
    // ---- odd P2: read a47[u+1]; stage A(u+3); MFMA(a03[u+1],b[u+1])
    LDA4(aQ1, u + 1, 4);
    if (s3) STAGE_A(u + 3);
    BAR(); LGKM0();
    MM16(aC1, bC1, 0);
    if (s3) VMBAR(4); else VMBAR(0);                 // unit u+2 landed
    // ---- next even P1: read a03[u+2],b[u+2]; stage B(u+4); MFMA(a47[u+1],b[u+1])
    if (s2) { LDA4(aC0, u + 2, 0); LDB4(bC0, u + 2); }
    if (s4) STAGE_B(u + 4);
    BAR(); LGKM0();
    MM16(aQ1, bC1, 4);
    BAR();
  }

  // D col = lane&15, row = quad*4 + r (verified mapping)
#pragma unroll
  for (int i = 0; i < 8; ++i)
#pragma unroll
    for (int j = 0; j < 4; ++j) {
#pragma unroll
      for (int r = 0; r < 4; ++r) {
        int grow = m0 + wm + i * 16 + quad * 4 + r;
        int gcol = n0 + wn + j * 16 + fr;
        cstore(&C[(size_t)grow * N + gcol], acc[i][j][r]);
      }
    }
#undef AB_
#undef BB_
#undef STAGE_A
#undef STAGE_B
#undef LDA4
#undef LDB4
#undef MM16
#undef BAR
#undef LGKM0
#undef VMBAR
}

// ---------------------------------------------------------------------------
// x_dbl MFMA GEMM: xdbl[M,36pad] = xs[M,2048] * Wx_bf[64,2048]^T.
// BM=64, BK=64, 4 waves; wave w owns row-tile w, 3 col-tiles. grid = MR/64.
// Output row layout: dt at col 0, B at 4..19, C at 20..35.
// ---------------------------------------------------------------------------
__global__ __launch_bounds__(256) void xdbl_mfma(
    const bf16_t* __restrict__ xs, const bf16_t* __restrict__ Wx_bf,
    float* __restrict__ xdbl)
{
  __shared__ __align__(16) bf16_t As[2 * 64 * 32];
  __shared__ __align__(16) bf16_t Bs[2 * 64 * 32];
  const int tid  = threadIdx.x;
  const int wave = tid >> 6;
  const int lane = tid & 63;
  const int m0 = blockIdx.x * 64;
  const int fr = lane & 15;
  const int quad = lane >> 4;

  const int srow = wave * 16 + (lane >> 2);
  const int scol = (lane & 3) * 8;
  const bf16_t* Ag = xs + (size_t)(m0 + srow) * DI + scol;
  const bf16_t* Bg = Wx_bf + (size_t)srow * DI + scol;
  bf16_t* lA = As + wave * 512;
  bf16_t* lB = Bs + wave * 512;

  f32x4 acc[3];
#pragma unroll
  for (int jt = 0; jt < 3; ++jt) acc[jt] = (f32x4){0.f, 0.f, 0.f, 0.f};

  for (int k0 = 0; k0 < DI; k0 += 64) {
    __syncthreads();
#pragma unroll
    for (int kk = 0; kk < 2; ++kk) {
      gld16(Ag + k0 + kk * 32, lA + kk * 2048);
      gld16(Bg + k0 + kk * 32, lB + kk * 2048);
    }
    __syncthreads();

#pragma unroll
    for (int kk = 0; kk < 2; ++kk) {
      bf16x8 a = *(const bf16x8*)&As[kk * 2048 + (wave * 16 + fr) * 32 + quad * 8];
#pragma unroll
      for (int jt = 0; jt < 3; ++jt) {
        bf16x8 b = *(const bf16x8*)&Bs[kk * 2048 + (jt * 16 + fr) * 32 + quad * 8];
        acc[jt] = __builtin_amdgcn_mfma_f32_16x16x32_bf16(a, b, acc[jt], 0, 0, 0);
      }
    }
  }

#pragma unroll
  for (int jt = 0; jt < 3; ++jt) {
#pragma unroll
    for (int r = 0; r < 4; ++r) {
      int grow = m0 + wave * 16 + quad * 4 + r;
      int j = jt * 16 + fr;
      if (j < 33) {
        int col = (j == 0) ? 0 : (j + 3);
        xdbl[(size_t)grow * XDW + col] = acc[jt][r];
      }
    }
  }
}

// ---------------------------------------------------------------------------
// Causal depthwise conv1d (k=4) + bias + SiLU.  bf16 xz -> bf16 xs.
// ---------------------------------------------------------------------------
__global__ __launch_bounds__(256) void conv_silu(
    const bf16_t* __restrict__ xz, const float* __restrict__ cw,
    const float* __restrict__ cb, bf16_t* __restrict__ xs)
{
  int idx = blockIdx.x * 256 + threadIdx.x;
  int d4 = idx & 511;
  int l  = (idx >> 9) & 2047;
  int b  = idx >> 20;
  int d  = d4 * 4;

  float wch[4][4];
#pragma unroll
  for (int c = 0; c < 4; ++c)
#pragma unroll
    for (int k = 0; k < 4; ++k) wch[c][k] = cw[(d + c) * 4 + k];

  float acc0 = cb[d+0], acc1 = cb[d+1], acc2 = cb[d+2], acc3 = cb[d+3];
  size_t rowbase = ((size_t)b * LL + l) * 4096 + d;
#pragma unroll
  for (int k = 0; k < 4; ++k) {
    if (l - 3 + k >= 0) {
      ushort4 u = *(const ushort4*)(xz + rowbase - (size_t)(3 - k) * 4096);
      acc0 += b2f(u.x) * wch[0][k];
      acc1 += b2f(u.y) * wch[1][k];
      acc2 += b2f(u.z) * wch[2][k];
      acc3 += b2f(u.w) * wch[3][k];
    }
  }
  ushort4 o;
  o.x = f2bn(silu(acc0)); o.y = f2bn(silu(acc1));
  o.z = f2bn(silu(acc2)); o.w = f2bn(silu(acc3));
  *(ushort4*)(xs + ((size_t)b * LL + l) * (size_t)DI + d) = o;
}

// ---------------------------------------------------------------------------
// Scan pass 1: per (b, chunk) scan from h=0; ONE channel per thread.
// grid: 1024 = b(8) x chunk(16) x dgroup(8); thread covers d = dg*256+tid.
// FAST PATH: A[d,n] = -(n+1) => exp2(dt*A2[n]) = w^(n+1), w = exp2(dt*A2_0).
// R8: PACKED fp32 (f32x2 -> v_pk_fma_f32/v_pk_mul_f32, 2 f32/instr) for the
// h-update and the w-power chain (wv2[k] = wv2[k-1] * w^2); B loaded as f32x2.
// Per-step VALU instr ~70 -> ~42.  Same fma precision; only ulp-level
// regrouping vs scalar.  Verified per thread vs A_log; block-uniform
// fallback otherwise.  states: [b][c][d][32] fp32 (0..15 P, 16..31 h_end).
// ---------------------------------------------------------------------------
__global__ __launch_bounds__(256) void scan_pass1(
    const float* __restrict__ xdbl, const bf16_t* __restrict__ xs,
    const float* __restrict__ W_dt, const float* __restrict__ b_dt,
    const float* __restrict__ A_log, float* __restrict__ states)
{
  const int bid = blockIdx.x;
  const int dg = bid & 7, c = (bid >> 3) & 15, b = bid >> 7;
  const int d = dg * 256 + threadIdx.x;

  const float A2_0 = -__expf(A_log[(size_t)d * NST]) * 1.44269504f;
  bool ok = true;
#pragma unroll
  for (int n = 1; n < NST; ++n) {
    float a = -__expf(A_log[(size_t)d * NST + n]) * 1.44269504f;
    ok = ok && (fabsf(a - (float)(n + 1) * A2_0) <= 1e-3f * (float)(n + 1));
  }
  __shared__ int s_ok;
  __shared__ __align__(16) float sx[64 * XDW];
  if (threadIdx.x == 0) s_ok = 1;
  __syncthreads();
  if (!ok) s_ok = 0;           // benign race: only 0 is written
  __syncthreads();
  const bool fast = (s_ok != 0);

  const float wdt = W_dt[d], bdt = b_dt[d];
  float dts = 0.f;
  const size_t rbase = (size_t)b * LL + c * CLEN;
  float xv = b2f(xs[rbase * DI + d]);
  const bf16_t* xp = xs + (rbase + 1) * DI + d;   // next-step x pointer

  if (fast) {
    f32x2 h2[8];
#pragma unroll
    for (int k = 0; k < 8; ++k) h2[k] = (f32x2){0.f, 0.f};
    for (int s = 0; s < CLEN; s += 64) {
      __syncthreads();
      const float4* xg4 = (const float4*)(xdbl + (rbase + s) * XDW);
      float4* sx4 = (float4*)sx;
      for (int q = threadIdx.x; q < (64 * XDW) / 4; q += 256) sx4[q] = xg4[q];
      __syncthreads();
#pragma unroll 2
      for (int u = 0; u < 64; ++u) {
        int tn = s + u + 1;
        float nx = 0.f;
        if (tn < CLEN) nx = b2f(*xp);
        xp += DI;
        float dtr = sx[u * XDW];
        float dt = softplus(fmaf(dtr, wdt, bdt));
        dts += dt;
        float dx = dt * xv;
        float w = exp2f(dt * A2_0);
        float w2 = w * w;
        f32x2 wv2[8];
        wv2[0] = (f32x2){w, w2};
        const f32x2 w2v = (f32x2){w2, w2};
#pragma unroll
        for (int k = 1; k < 8; ++k) wv2[k] = wv2[k - 1] * w2v;
        const f32x2* B2 = (const f32x2*)&sx[u * XDW + 4];
        const f32x2 dx2 = (f32x2){dx, dx};
#pragma unroll
        for (int k = 0; k < 8; ++k)
          h2[k] = wv2[k] * h2[k] + dx2 * B2[k];
        xv = nx;
      }
    }
    size_t sb = (((size_t)b * NCH + c) * DI + d) * 32;
    float W0 = exp2f(dts * A2_0);
    float W2 = W0 * W0;
    f32x2 Wv2[8];
    Wv2[0] = (f32x2){W0, W2};
    const f32x2 W2v = (f32x2){W2, W2};
#pragma unroll
    for (int k = 1; k < 8; ++k) Wv2[k] = Wv2[k - 1] * W2v;
    f32x2* sp = (f32x2*)(states + sb);
#pragma unroll
    for (int k = 0; k < 8; ++k) { sp[k] = Wv2[k]; sp[8 + k] = h2[k]; }
  } else {
    float A2[NST], h[NST];
#pragma unroll
    for (int n = 0; n < NST; ++n) {
      A2[n] = -__expf(A_log[(size_t)d * NST + n]) * 1.44269504f;
      h[n] = 0.f;
    }
    for (int s = 0; s < CLEN; s += 64) {
      __syncthreads();
      const float* xg = xdbl + (rbase + s) * XDW;
      for (int q = threadIdx.x; q < 64 * XDW; q += 256) sx[q] = xg[q];
      __syncthreads();
#pragma unroll 2
      for (int u = 0; u < 64; ++u) {
        int tn = s + u + 1;
        float nx = 0.f;
        if (tn < CLEN) nx = b2f(*xp);
        xp += DI;
        float dtr = sx[u * XDW];
        float dt = softplus(fmaf(dtr, wdt, bdt));
        dts += dt;
        float dx = dt * xv;
        const float4* Bp = (const float4*)&sx[u * XDW + 4];
#pragma unroll
        for (int n4 = 0; n4 < 4; ++n4) {
          float4 Bv = Bp[n4];
          float bb[4] = {Bv.x, Bv.y, Bv.z, Bv.w};
#pragma unroll
          for (int k = 0; k < 4; ++k) {
            int n = n4 * 4 + k;
            h[n] = fmaf(exp2f(dt * A2[n]), h[n], dx * bb[k]);
          }
        }
        xv = nx;
      }
    }
    size_t sb = (((size_t)b * NCH + c) * DI + d) * 32;
#pragma unroll
    for (int n = 0; n < NST; ++n) {
      states[sb + n]      = exp2f(dts * A2[n]);
      states[sb + 16 + n] = h[n];
    }
  }
}

// ---------------------------------------------------------------------------
// Scan pass 2: compose chunk states sequentially; h_init -> P slot (in place).
// ---------------------------------------------------------------------------
__global__ __launch_bounds__(256) void scan_pass2(float* __restrict__ states)
{
  int t = blockIdx.x * 256 + threadIdx.x;    // 8*2048*16 = 262144
  int n = t & 15, d = (t >> 4) & 2047, b = t >> 15;
  float h = 0.f;
  for (int c = 0; c < NCH; ++c) {
    size_t sb = (((size_t)b * NCH + c) * DI + d) * 32;
    float P  = states[sb + n];
    float h0 = states[sb + 16 + n];
    states[sb + n] = h;          // h_init entering chunk c
    h = fmaf(P, h, h0);
  }
}

// ---------------------------------------------------------------------------
// Scan pass 3: re-scan from h_init; y = C.h + D*x; gate SiLU(z); bf16 in place.
// ONE channel per thread; packed-f32 fast path like pass 1 (y accumulated as
// f32x2 then horizontal-added -- reassociation within 5.5e-4 budget).
// ---------------------------------------------------------------------------
__global__ __launch_bounds__(256) void scan_pass3(
    const float* __restrict__ xdbl, const bf16_t* __restrict__ xz,
    bf16_t* __restrict__ xs, const float* __restrict__ states,
    const float* __restrict__ W_dt, const float* __restrict__ b_dt,
    const float* __restrict__ A_log, const float* __restrict__ Dp)
{
  const int bid = blockIdx.x;
  const int dg = bid & 7, c = (bid >> 3) & 15, b = bid >> 7;
  const int d = dg * 256 + threadIdx.x;

  const float A2_0 = -__expf(A_log[(size_t)d * NST]) * 1.44269504f;
  bool ok = true;
#pragma unroll
  for (int n = 1; n < NST; ++n) {
    float a = -__expf(A_log[(size_t)d * NST + n]) * 1.44269504f;
    ok = ok && (fabsf(a - (float)(n + 1) * A2_0) <= 1e-3f * (float)(n + 1));
  }
  __shared__ int s_ok;
  __shared__ __align__(16) float sx[64 * XDW];
  if (threadIdx.x == 0) s_ok = 1;
  __syncthreads();
  if (!ok) s_ok = 0;
  __syncthreads();
  const bool fast = (s_ok != 0);

  size_t sb = (((size_t)b * NCH + c) * DI + d) * 32;
  const float wdt = W_dt[d], bdt = b_dt[d];
  const float Dd = Dp[d];
  const size_t rbase = (size_t)b * LL + c * CLEN;

  float xv = b2f(xs[rbase * DI + d]);
  float zv = b2f(xz[rbase * 4096 + DI + d]);
  const bf16_t* xp = xs + (rbase + 1) * DI + d;
  const bf16_t* zp = xz + (rbase + 1) * 4096 + DI + d;
  bf16_t* op = xs + rbase * DI + d;

  if (fast) {
    f32x2 h2[8];
    const f32x2* hp = (const f32x2*)(states + sb);
#pragma unroll
    for (int k = 0; k < 8; ++k) h2[k] = hp[k];
    for (int s = 0; s < CLEN; s += 64) {
      __syncthreads();
      const float4* xg4 = (const float4*)(xdbl + (rbase + s) * XDW);
      float4* sx4 = (float4*)sx;
      for (int q = threadIdx.x; q < (64 * XDW) / 4; q += 256) sx4[q] = xg4[q];
      __syncthreads();
#pragma unroll 2
      for (int u = 0; u < 64; ++u) {
        int tn = s + u + 1;
        float nx = 0.f, nz = 0.f;
        if (tn < CLEN) { nx = b2f(*xp); nz = b2f(*zp); }
        xp += DI; zp += 4096;
        float dtr = sx[u * XDW];
        float dt = softplus(fmaf(dtr, wdt, bdt));
        float dx = dt * xv;
        float w = exp2f(dt * A2_0);
        float w2 = w * w;
        f32x2 wv2[8];
        wv2[0] = (f32x2){w, w2};
        const f32x2 w2v = (f32x2){w2, w2};
#pragma unroll
        for (int k = 1; k < 8; ++k) wv2[k] = wv2[k - 1] * w2v;
        const f32x2* B2 = (const f32x2*)&sx[u * XDW + 4];
        const f32x2* C2 = (const f32x2*)&sx[u * XDW + 20];
        const f32x2 dx2 = (f32x2){dx, dx};
        f32x2 y2 = (f32x2){Dd * xv, 0.f};
#pragma unroll
        for (int k = 0; k < 8; ++k) {
          h2[k] = wv2[k] * h2[k] + dx2 * B2[k];
          y2 = h2[k] * C2[k] + y2;
        }
        float y = y2.x + y2.y;
        *op = f2bn(y * silu(zv));
        op += DI;
        xv = nx; zv = nz;
      }
    }
  } else {
    float A2[NST], h[NST];
#pragma unroll
    for (int n = 0; n < NST; ++n) {
      A2[n] = -__expf(A_log[(size_t)d * NST + n]) * 1.44269504f;
      h[n] = states[sb + n];
    }
    for (int s = 0; s < CLEN; s += 64) {
      __syncthreads();
      const float* xg = xdbl + (rbase + s) * XDW;
      for (int q = threadIdx.x; q < 64 * XDW; q += 256) sx[q] = xg[q];
      __syncthreads();
#pragma unroll 2
      for (int u = 0; u < 64; ++u) {
        int tn = s + u + 1;
        float nx = 0.f, nz = 0.f;
        if (tn < CLEN) { nx = b2f(*xp); nz = b2f(*zp); }
        xp += DI; zp += 4096;
        float dtr = sx[u * XDW];
        float dt = softplus(fmaf(dtr, wdt, bdt));
        float dx = dt * xv;
        float y = Dd * xv;
        const float4* Bp = (const float4*)&sx[u * XDW + 4];
        const float4* Cp = (const float4*)&sx[u * XDW + 20];
#pragma unroll
        for (int n4 = 0; n4 < 4; ++n4) {
          float4 Bv = Bp[n4];
          float4 Cv = Cp[n4];
          float bb[4] = {Bv.x, Bv.y, Bv.z, Bv.w};
          float cc[4] = {Cv.x, Cv.y, Cv.z, Cv.w};
#pragma unroll
          for (int k = 0; k < 4; ++k) {
            int n = n4 * 4 + k;
            h[n] = fmaf(exp2f(dt * A2[n]), h[n], dx * bb[k]);
            y = fmaf(h[n], cc[k], y);
          }
        }
        *op = f2bn(y * silu(zv));
        op += DI;
        xv = nx; zv = nz;
      }
    }
  }
}

// ---------------------------------------------------------------------------
extern "C" void kernel_launch(void* const* d_in, const int* in_sizes, int n_in,
                              void* d_out, int out_size, void* d_ws, size_t ws_size,
                              hipStream_t stream)
{
  const float* x     = (const float*)d_in[0];
  const float* W_in  = (const float*)d_in[1];
  const float* cw    = (const float*)d_in[2];
  const float* cb    = (const float*)d_in[3];
  const float* W_x   = (const float*)d_in[4];
  const float* W_dt  = (const float*)d_in[5];
  const float* b_dt  = (const float*)d_in[6];
  const float* A_log = (const float*)d_in[7];
  const float* Dp    = (const float*)d_in[8];
  const float* W_out = (const float*)d_in[9];
  float* out = (float*)d_out;

  // ws (proven-safe footprint): xz bf16 [16384,4096] | xs bf16 [16384,2048]
  bf16_t* xz = (bf16_t*)d_ws;
  bf16_t* xs = xz + (size_t)MR * 4096;

  // d_out (64 MiB fp32) as phase-disjoint scratch:
  //   conversions: x_bf [0,32M) | Win_bf [32M,40M) | Wx_bf [40M,40.25M)
  //   scan:        states [0,33.6M) | xdbl [33.6M,36M)  (x_bf/Win_bf dead)
  //   GEMM3 output overwrites everything last.
  bf16_t* x_bf    = (bf16_t*)d_out;
  bf16_t* Win_bf  = x_bf + (size_t)MR * DMOD;
  bf16_t* Wx_bf   = Win_bf + (size_t)4096 * DMOD;
  float*  states  = (float*)d_out;
  float*  xdbl    = states + (size_t)BB * NCH * DI * 32;   // 8.39M floats in
  bf16_t* Wout_bf = xz;   // overlays dead xz after scan pass 3

  // 0) operand conversions
  cvt_bf16<<<(MR*DMOD/4 + 255)/256, 256, 0, stream>>>(x, x_bf, MR*DMOD/4);
  cvt_bf16<<<(4096*DMOD/4 + 255)/256, 256, 0, stream>>>(W_in, Win_bf, 4096*DMOD/4);
  cvt_wx<<<(64*DI)/256, 256, 0, stream>>>(W_x, Wx_bf);
  // 1) xz = x @ W_in^T   (M=16384, N=4096, K=1024) phase-pipelined 256^2
  mgemm_p3<bf16_t><<<dim3(4096/256, MR/256), 512, 0, stream>>>(x_bf, Win_bf, xz, 4096, DMOD);
  // 2) causal depthwise conv + bias + SiLU -> xs (bf16)
  conv_silu<<<(BB*LL*512)/256, 256, 0, stream>>>(xz, cw, cb, xs);
  // 3) x_dbl (padded rows) = xs @ W_x^T (MFMA)
  xdbl_mfma<<<MR/64, 256, 0, stream>>>(xs, Wx_bf, xdbl);
  // 4) chunked selective scan (3 passes) + D*xs + SiLU(z) gate, in place in xs
  scan_pass1<<<BB*NCH*8, 256, 0, stream>>>(xdbl, xs, W_dt, b_dt, A_log, states);
  scan_pass2<<<(BB*DI*NST)/256, 256, 0, stream>>>(states);
  scan_pass3<<<BB*NCH*8, 256, 0, stream>>>(xdbl, xz, xs, states, W_dt, b_dt, A_log, Dp);
  // 5) W_out -> bf16 (dead xz region), then out = gated @ W_out^T
  cvt_bf16<<<(DMOD*DI/4 + 255)/256, 256, 0, stream>>>(W_out, Wout_bf, DMOD*DI/4);
  // out = gated @ W_out^T  (M=16384, N=1024, K=2048)
  mgemm_p3<float><<<dim3(DMOD/256, MR/256), 512, 0, stream>>>(xs, Wout_bf, out, DMOD, DI);
}